// Round 4
// baseline (337.486 us; speedup 1.0000x reference)
//
#include <hip/hip_runtime.h>
#include <hip/hip_fp16.h>

// Problem constants (H=W=2048, C=3, KSIZE=2, SIGMA=2, ITERATIONS=2)
#define Hh 2048
#define Ww 2048
#define HW (2048 * 2048)
constexpr int REG = 2045;              // Hv = Wv = H - 2*KSIZE + 1
constexpr int RBASE = 2 * 2045 * 2045; // i-plane stride of `off` in elements
constexpr int SWAP_D2 = 589824;        // 768^2
constexpr int CLEAN_D2 = 586756;       // 766^2

// Gaussian kernel sigma=2, truncate=4 -> radius 8, normalized (precomputed)
__device__ __constant__ float GK[17] = {
    6.691628e-05f, 4.363490e-04f, 2.215963e-03f, 8.764304e-03f,
    2.699596e-02f, 6.475994e-02f, 1.209875e-01f, 1.760358e-01f,
    1.9947466e-01f, 1.760358e-01f, 1.209875e-01f, 6.475994e-02f,
    2.699596e-02f, 8.764304e-03f, 2.215963e-03f, 4.363490e-04f,
    6.691628e-05f};

struct F3 { float x, y, z; };

// ---------------------------------------------------------------------------
// Pass 1: gather-formulated glass swap + fp16 planar repack. 4 px/thread for
// ILP on the latency-bound scattered img gather. Candidate orders are monotone
// in the scan sequence -> last-hit-wins, zero order arithmetic (verified R2).
// Halo q packed 4 B: (dw0+2)|(dh0+2)<<8|(dw1+2)<<16|(dh1+2)<<24, 0xFFFFFFFF
// sentinel where region/swap mask is false.
// ---------------------------------------------------------------------------
constexpr int TX = 64, TY = 16;
constexpr int HX = TX + 3, HY = TY + 3;  // 67 x 19 halo

__global__ __launch_bounds__(256) void swap_gather(
    const float* __restrict__ img, const int* __restrict__ off,
    __half* __restrict__ A) {
  int x0 = blockIdx.x * TX, y0 = blockIdx.y * TY;
  int tx4 = (threadIdx.x & 15) * 4, ty = threadIdx.x >> 4;
  int px = x0 + tx4, py = y0 + ty;
  int plin = py * Ww + px;

  // Block-uniform fast path: halo entirely inside clean circle -> no writers.
  int mxx = max(abs(1024 - (x0 - 1)), abs(1024 - (x0 + TX + 1)));
  int mxy = max(abs(1024 - (y0 - 1)), abs(1024 - (y0 + TY + 1)));
  if (mxx * mxx + mxy * mxy < SWAP_D2) {
    const float4 c0 = *(const float4*)(img + (size_t)plin * 3);
    const float4 c1 = *(const float4*)(img + (size_t)plin * 3 + 4);
    const float4 c2 = *(const float4*)(img + (size_t)plin * 3 + 8);
    float v[12] = {c0.x, c0.y, c0.z, c0.w, c1.x, c1.y, c1.z, c1.w,
                   c2.x, c2.y, c2.z, c2.w};
#pragma unroll
    for (int c = 0; c < 3; ++c) {
      __half2 h01 = __float22half2_rn(make_float2(v[c], v[3 + c]));
      __half2 h23 = __float22half2_rn(make_float2(v[6 + c], v[9 + c]));
      uint2 o = make_uint2(*(unsigned*)&h01, *(unsigned*)&h23);
      *(uint2*)&A[(size_t)c * HW + plin] = o;
    }
    return;  // block-uniform: no divergence vs the __syncthreads below
  }

  __shared__ unsigned sh[HY * HX];
  for (int e = threadIdx.x; e < HY * HX; e += 256) {
    int ly = e / HX, lx = e - ly * HX;
    int qy = y0 - 1 + ly, qx = x0 - 1 + lx;
    unsigned v = 0xFFFFFFFFu;
    int dcx = 1024 - qx, dcy = 1024 - qy;
    if (qy >= 2 && qy <= 2046 && qx >= 2 && qx <= 2046 &&
        dcx * dcx + dcy * dcy >= SWAP_D2) {
      int base = ((qy - 2) * REG + (qx - 2)) * 2;
      const int2 a0 = *(const int2*)&off[base];          // {dh0, dw0}
      const int2 a1 = *(const int2*)&off[RBASE + base];  // {dh1, dw1}
      v = (unsigned)(a0.y + 2) | ((unsigned)(a0.x + 2) << 8) |
          ((unsigned)(a1.y + 2) << 16) | ((unsigned)(a1.x + 2) << 24);
    }
    sh[e] = v;
  }
  __syncthreads();

  unsigned w[4][7];
#pragma unroll
  for (int dyi = 0; dyi < 4; ++dyi)
#pragma unroll
    for (int c = 0; c < 7; ++c) w[dyi][c] = sh[(ty + dyi) * HX + tx4 + c];

  int so[4] = {0, 0, 0, 0};

#define CANDC(dyi, dxi) \
  ((unsigned)((1 - (dxi)) + 2) | ((unsigned)((1 - (dyi)) + 2) << 8))
#define OFFC(dyi, dxi) (-(1 - (dyi)) * Ww - (1 - (dxi)))
#define C0(j, dyi, dxi) \
  if ((w[dyi][(j) + (dxi)] & 0xFFFFu) == CANDC(dyi, dxi)) so[j] = OFFC(dyi, dxi);
#define C1(j, dyi, dxi) \
  if ((w[dyi][(j) + (dxi)] >> 16) == CANDC(dyi, dxi)) so[j] = OFFC(dyi, dxi);
#define PXSEQ(j)                                                        \
  C0(j, 0, 0) C0(j, 0, 1) C0(j, 0, 2) C0(j, 0, 3)                       \
  C0(j, 1, 0) C0(j, 1, 1) C0(j, 1, 2) C0(j, 1, 3)                       \
  C0(j, 2, 0) C0(j, 2, 1) C0(j, 2, 2) C0(j, 2, 3)                       \
  C0(j, 3, 0) C0(j, 3, 1) C0(j, 3, 2) C0(j, 3, 3)                       \
  C1(j, 0, 0) C1(j, 0, 1) C1(j, 0, 2) C1(j, 0, 3)                       \
  C1(j, 1, 0)                                                           \
  { unsigned wc = w[1][(j) + 1];                                        \
    if ((wc >> 24) != 0xFFu) {                                          \
      int dh1 = (int)((wc >> 24) & 0xFFu) - 2;                          \
      int dw1 = (int)((wc >> 16) & 0xFFu) - 2;                          \
      so[j] = dh1 * Ww + dw1; } }                                       \
  C1(j, 1, 1) C1(j, 1, 2) C1(j, 1, 3)                                   \
  C1(j, 2, 0) C1(j, 2, 1) C1(j, 2, 2) C1(j, 2, 3)                       \
  C1(j, 3, 0) C1(j, 3, 1) C1(j, 3, 2) C1(j, 3, 3)

  PXSEQ(0) PXSEQ(1) PXSEQ(2) PXSEQ(3)
#undef CANDC
#undef OFFC
#undef C0
#undef C1
#undef PXSEQ

  // 4 independent 12 B gathers (ILP), then packed 8 B stores per plane.
  F3 g[4];
#pragma unroll
  for (int j = 0; j < 4; ++j)
    g[j] = *(const F3*)(img + (size_t)(plin + j + so[j]) * 3);
  {
    __half2 h01 = __float22half2_rn(make_float2(g[0].x, g[1].x));
    __half2 h23 = __float22half2_rn(make_float2(g[2].x, g[3].x));
    *(uint2*)&A[plin] = make_uint2(*(unsigned*)&h01, *(unsigned*)&h23);
  }
  {
    __half2 h01 = __float22half2_rn(make_float2(g[0].y, g[1].y));
    __half2 h23 = __float22half2_rn(make_float2(g[2].y, g[3].y));
    *(uint2*)&A[HW + plin] = make_uint2(*(unsigned*)&h01, *(unsigned*)&h23);
  }
  {
    __half2 h01 = __float22half2_rn(make_float2(g[0].z, g[1].z));
    __half2 h23 = __float22half2_rn(make_float2(g[2].z, g[3].z));
    *(uint2*)&A[2 * HW + plin] = make_uint2(*(unsigned*)&h01, *(unsigned*)&h23);
  }
}

// ---------------------------------------------------------------------------
// Pass 2 (fused): vblur + hblur + clip + compose, 2D-tiled. Out tile 112x32.
// Stage A (fp16) 48 rows x 128 halves in LDS; vblur in registers (4 row-groups
// x 64 col-pairs = 256 threads) -> fp32 sMid; hblur from sMid (32 rows x 8 col
// groups of 14); compose with clean circle and write out. Eliminates the B
// buffer entirely (48 MB round-trip) and one launch.
// ---------------------------------------------------------------------------
constexpr int BTX = 112, BTY = 32;
constexpr int SROWS = BTY + 16;   // 48 staged rows
constexpr int SCOLU = 64;         // 128 staged halves = 64 uints
constexpr int MSTR = 130;         // sMid row stride (floats), even + pad

__global__ __launch_bounds__(256) void blur_compose(
    const __half* __restrict__ A, const float* __restrict__ img,
    float* __restrict__ out) {
  __shared__ unsigned sIn[SROWS * SCOLU];   // 12 KB
  __shared__ float sMid[BTY * MSTR];        // 16.6 KB
  int x0 = blockIdx.x * BTX;
  int y0 = blockIdx.y * BTY;
  int tid = threadIdx.x;
  int cu = tid & 63, rg = tid >> 6;  // phase-2 role
  int rr = tid >> 3, cg = tid & 7;   // phase-3 role

  for (int c = 0; c < 3; ++c) {
    const __half* Ap = A + (size_t)c * HW;
    __syncthreads();  // prev channel's phase 3 done before overwriting
    // ---- stage sIn: rows [y0-8, y0+40), half-cols [x0-8, x0+120), clamped
#pragma unroll
    for (int k = 0; k < 12; ++k) {
      int e = tid + k * 256;
      int row = e >> 6, u = e & 63;
      int gy = y0 - 8 + row;
      gy = gy < 0 ? 0 : (gy > Hh - 1 ? Hh - 1 : gy);
      int gx = x0 - 8 + 2 * u;
      unsigned v;
      if (gx >= 0 && gx + 1 <= Ww - 1) {
        v = *(const unsigned*)&Ap[(size_t)gy * Ww + gx];
      } else {
        int xlo = gx < 0 ? 0 : (gx > Ww - 1 ? Ww - 1 : gx);
        int xg1 = gx + 1;
        int xhi = xg1 < 0 ? 0 : (xg1 > Ww - 1 ? Ww - 1 : xg1);
        __half2 h;
        h.x = Ap[(size_t)gy * Ww + xlo];
        h.y = Ap[(size_t)gy * Ww + xhi];
        v = *(unsigned*)&h;
      }
      sIn[e] = v;
    }
    __syncthreads();
    // ---- phase 2: vertical blur, 8 rows x 2 half-cols per thread
    float acc[8][2];
#pragma unroll
    for (int r = 0; r < 8; ++r) acc[r][0] = acc[r][1] = 0.f;
#pragma unroll
    for (int j = 0; j < 24; ++j) {
      unsigned raw = sIn[(rg * 8 + j) * SCOLU + cu];
      float2 v = __half22float2(*(__half2*)&raw);
#pragma unroll
      for (int r = 0; r < 8; ++r) {
        int t = j - r;
        if (t >= 0 && t <= 16) {
          acc[r][0] += GK[t] * v.x;
          acc[r][1] += GK[t] * v.y;
        }
      }
    }
#pragma unroll
    for (int r = 0; r < 8; ++r) {
      *(float2*)&sMid[(rg * 8 + r) * MSTR + 2 * cu] =
          make_float2(acc[r][0], acc[r][1]);
    }
    __syncthreads();
    // ---- phase 3: horizontal blur + compose, row rr, 14 cols at cg*14
    int y = y0 + rr;
    const float* srow = &sMid[rr * MSTR + cg * 14];
    float f[30];
#pragma unroll
    for (int j = 0; j < 15; ++j) {
      float2 v = *(const float2*)&srow[2 * j];
      f[2 * j] = v.x;
      f[2 * j + 1] = v.y;
    }
    int dyc = 1024 - y;
    bool yok = (y >= 2 && y <= 2046);
#pragma unroll
    for (int k = 0; k < 14; ++k) {
      int x = x0 + cg * 14 + k;
      if (x < Ww) {
        float s = 0.f;
#pragma unroll
        for (int j = 0; j < 17; ++j) s += GK[j] * f[k + j];
        int dxc = 1024 - x;
        bool clean =
            yok && x >= 2 && x <= 2046 && dxc * dxc + dyc * dyc < CLEAN_D2;
        int p3 = (y * Ww + x) * 3 + c;
        float vout;
        if (clean) {
          vout = img[p3];
        } else {
          vout = s < 0.f ? 0.f : (s > 255.f ? 255.f : s);
        }
        out[p3] = vout;
      }
    }
  }
}

extern "C" void kernel_launch(void* const* d_in, const int* in_sizes, int n_in,
                              void* d_out, int out_size, void* d_ws,
                              size_t ws_size, hipStream_t stream) {
  const float* img = (const float*)d_in[0];
  const int* off = (const int*)d_in[1];
  float* out = (float*)d_out;

  // Workspace: A (fp16 x 3 planes, 24 MB)
  __half* A = (__half*)d_ws;

  swap_gather<<<dim3(Ww / TX, Hh / TY), 256, 0, stream>>>(img, off, A);
  blur_compose<<<dim3((Ww + BTX - 1) / BTX, Hh / BTY), 256, 0, stream>>>(
      A, img, out);
}

// Round 5
// 187.904 us; speedup vs baseline: 1.7961x; 1.7961x over previous
//
#include <hip/hip_runtime.h>
#include <hip/hip_fp16.h>

// Problem constants (H=W=2048, C=3, KSIZE=2, SIGMA=2, ITERATIONS=2)
#define Hh 2048
#define Ww 2048
#define HW (2048 * 2048)
constexpr int REG = 2045;              // Hv = Wv = H - 2*KSIZE + 1
constexpr int RBASE = 2 * 2045 * 2045; // i-plane stride of `off` in elements
constexpr int SWAP_D2 = 589824;        // 768^2
constexpr int CLEAN_D2 = 586756;       // 766^2
// A[q] is consumed only within L-inf 8 of a non-clean pixel; r + 8*sqrt(2) <
// 766  =>  r <= 754 is provably dead. 754^2:
constexpr int DEAD_D2 = 568516;

// Gaussian kernel sigma=2, truncate=4 -> radius 8, normalized (precomputed)
__device__ __constant__ float GK[17] = {
    6.691628e-05f, 4.363490e-04f, 2.215963e-03f, 8.764304e-03f,
    2.699596e-02f, 6.475994e-02f, 1.209875e-01f, 1.760358e-01f,
    1.9947466e-01f, 1.760358e-01f, 1.209875e-01f, 6.475994e-02f,
    2.699596e-02f, 8.764304e-03f, 2.215963e-03f, 4.363490e-04f,
    6.691628e-05f};

struct F3 { float x, y, z; };

// ---------------------------------------------------------------------------
// Pass 1: gather-formulated glass swap + fp16 planar repack. 4 px/thread for
// ILP on the latency-bound scattered img gather; last-hit-wins candidate scan
// (orders monotone in sequence, verified R2/R3). Deep-interior tiles (r<754)
// produce A that is never read downstream -> full skip.
// ---------------------------------------------------------------------------
constexpr int TX = 64, TY = 16;
constexpr int HX = TX + 3, HY = TY + 3;  // 67 x 19 halo

__global__ __launch_bounds__(256) void swap_gather(
    const float* __restrict__ img, const int* __restrict__ off,
    __half* __restrict__ A) {
  int x0 = blockIdx.x * TX, y0 = blockIdx.y * TY;

  // Dead-region skip: A never consumed where every tile pixel has d2 <= 754^2.
  int sdx = max(abs(1024 - x0), abs(1024 - (x0 + TX - 1)));
  int sdy = max(abs(1024 - y0), abs(1024 - (y0 + TY - 1)));
  if (sdx * sdx + sdy * sdy <= DEAD_D2) return;

  int tx4 = (threadIdx.x & 15) * 4, ty = threadIdx.x >> 4;
  int px = x0 + tx4, py = y0 + ty;
  int plin = py * Ww + px;

  // Fast path: halo entirely inside swap circle -> no writers -> src = p.
  int mxx = max(abs(1024 - (x0 - 1)), abs(1024 - (x0 + TX + 1)));
  int mxy = max(abs(1024 - (y0 - 1)), abs(1024 - (y0 + TY + 1)));
  if (mxx * mxx + mxy * mxy < SWAP_D2) {
    const float4 c0 = *(const float4*)(img + (size_t)plin * 3);
    const float4 c1 = *(const float4*)(img + (size_t)plin * 3 + 4);
    const float4 c2 = *(const float4*)(img + (size_t)plin * 3 + 8);
    float v[12] = {c0.x, c0.y, c0.z, c0.w, c1.x, c1.y, c1.z, c1.w,
                   c2.x, c2.y, c2.z, c2.w};
#pragma unroll
    for (int c = 0; c < 3; ++c) {
      __half2 h01 = __float22half2_rn(make_float2(v[c], v[3 + c]));
      __half2 h23 = __float22half2_rn(make_float2(v[6 + c], v[9 + c]));
      uint2 o = make_uint2(*(unsigned*)&h01, *(unsigned*)&h23);
      *(uint2*)&A[(size_t)c * HW + plin] = o;
    }
    return;  // block-uniform
  }

  __shared__ unsigned sh[HY * HX];
  for (int e = threadIdx.x; e < HY * HX; e += 256) {
    int ly = e / HX, lx = e - ly * HX;
    int qy = y0 - 1 + ly, qx = x0 - 1 + lx;
    unsigned v = 0xFFFFFFFFu;
    int dcx = 1024 - qx, dcy = 1024 - qy;
    if (qy >= 2 && qy <= 2046 && qx >= 2 && qx <= 2046 &&
        dcx * dcx + dcy * dcy >= SWAP_D2) {
      int base = ((qy - 2) * REG + (qx - 2)) * 2;
      const int2 a0 = *(const int2*)&off[base];          // {dh0, dw0}
      const int2 a1 = *(const int2*)&off[RBASE + base];  // {dh1, dw1}
      v = (unsigned)(a0.y + 2) | ((unsigned)(a0.x + 2) << 8) |
          ((unsigned)(a1.y + 2) << 16) | ((unsigned)(a1.x + 2) << 24);
    }
    sh[e] = v;
  }
  __syncthreads();

  unsigned w[4][7];
#pragma unroll
  for (int dyi = 0; dyi < 4; ++dyi)
#pragma unroll
    for (int c = 0; c < 7; ++c) w[dyi][c] = sh[(ty + dyi) * HX + tx4 + c];

  int so[4] = {0, 0, 0, 0};

#define CANDC(dyi, dxi) \
  ((unsigned)((1 - (dxi)) + 2) | ((unsigned)((1 - (dyi)) + 2) << 8))
#define OFFC(dyi, dxi) (-(1 - (dyi)) * Ww - (1 - (dxi)))
#define C0(j, dyi, dxi) \
  if ((w[dyi][(j) + (dxi)] & 0xFFFFu) == CANDC(dyi, dxi)) so[j] = OFFC(dyi, dxi);
#define C1(j, dyi, dxi) \
  if ((w[dyi][(j) + (dxi)] >> 16) == CANDC(dyi, dxi)) so[j] = OFFC(dyi, dxi);
#define PXSEQ(j)                                                        \
  C0(j, 0, 0) C0(j, 0, 1) C0(j, 0, 2) C0(j, 0, 3)                       \
  C0(j, 1, 0) C0(j, 1, 1) C0(j, 1, 2) C0(j, 1, 3)                       \
  C0(j, 2, 0) C0(j, 2, 1) C0(j, 2, 2) C0(j, 2, 3)                       \
  C0(j, 3, 0) C0(j, 3, 1) C0(j, 3, 2) C0(j, 3, 3)                       \
  C1(j, 0, 0) C1(j, 0, 1) C1(j, 0, 2) C1(j, 0, 3)                       \
  C1(j, 1, 0)                                                           \
  { unsigned wc = w[1][(j) + 1];                                        \
    if ((wc >> 24) != 0xFFu) {                                          \
      int dh1 = (int)((wc >> 24) & 0xFFu) - 2;                          \
      int dw1 = (int)((wc >> 16) & 0xFFu) - 2;                          \
      so[j] = dh1 * Ww + dw1; } }                                       \
  C1(j, 1, 1) C1(j, 1, 2) C1(j, 1, 3)                                   \
  C1(j, 2, 0) C1(j, 2, 1) C1(j, 2, 2) C1(j, 2, 3)                       \
  C1(j, 3, 0) C1(j, 3, 1) C1(j, 3, 2) C1(j, 3, 3)

  PXSEQ(0) PXSEQ(1) PXSEQ(2) PXSEQ(3)
#undef CANDC
#undef OFFC
#undef C0
#undef C1
#undef PXSEQ

  F3 g[4];
#pragma unroll
  for (int j = 0; j < 4; ++j)
    g[j] = *(const F3*)(img + (size_t)(plin + j + so[j]) * 3);
  {
    __half2 h01 = __float22half2_rn(make_float2(g[0].x, g[1].x));
    __half2 h23 = __float22half2_rn(make_float2(g[2].x, g[3].x));
    *(uint2*)&A[plin] = make_uint2(*(unsigned*)&h01, *(unsigned*)&h23);
  }
  {
    __half2 h01 = __float22half2_rn(make_float2(g[0].y, g[1].y));
    __half2 h23 = __float22half2_rn(make_float2(g[2].y, g[3].y));
    *(uint2*)&A[HW + plin] = make_uint2(*(unsigned*)&h01, *(unsigned*)&h23);
  }
  {
    __half2 h01 = __float22half2_rn(make_float2(g[0].z, g[1].z));
    __half2 h23 = __float22half2_rn(make_float2(g[2].z, g[3].z));
    *(uint2*)&A[2 * HW + plin] = make_uint2(*(unsigned*)&h01, *(unsigned*)&h23);
  }
}

// ---------------------------------------------------------------------------
// Pass 2: vertical 17-tap blur (R3 structure: 4 cols x 16 rows per thread,
// XCD band swizzle). Per-thread dead-column skip: B[y,x'] is read only if a
// non-clean output exists in row y within 8 cols of x'; columns >=8 px inside
// the clean circle can return without loading/storing anything.
// ---------------------------------------------------------------------------
constexpr int YPT = 16;
__global__ __launch_bounds__(256) void vblur(const __half* __restrict__ A,
                                             __half* __restrict__ B) {
  int b = blockIdx.x;
  int xcd = b & 7, r = b >> 3;          // 768 blocks: r in [0,96)
  int ystrip = (xcd << 4) | (r & 15);   // 128 strips, 16 per XCD band
  int rem = r >> 4;                     // 0..5
  int xb = rem & 1, c = rem >> 1;
  int x0 = (xb * 256 + threadIdx.x) * 4;
  int y0 = ystrip * YPT;

  // Dead-column skip (conservative, see header comment).
  int adx = max(abs(1024 - x0), abs(1024 - (x0 + 3))) + 8;
  int ady = max(abs(1024 - y0), abs(1024 - (y0 + YPT - 1)));
  if (y0 >= 2 && y0 + YPT - 1 <= 2046 && x0 >= 10 && x0 + 3 <= 2035 &&
      adx * adx + ady * ady < CLEAN_D2)
    return;

  const __half* Ap = A + (size_t)c * HW;
  __half* Bp = B + (size_t)c * HW;

  float acc[YPT][4];
#pragma unroll
  for (int k = 0; k < YPT; ++k)
#pragma unroll
    for (int q = 0; q < 4; ++q) acc[k][q] = 0.f;

#pragma unroll
  for (int j = 0; j < YPT + 16; ++j) {
    int ys = y0 - 8 + j;
    ys = ys < 0 ? 0 : (ys > Hh - 1 ? Hh - 1 : ys);  // mode='nearest'
    uint2 raw = *(const uint2*)&Ap[(size_t)ys * Ww + x0];
    __half2 h01 = *(__half2*)&raw.x;
    __half2 h23 = *(__half2*)&raw.y;
    float2 v01 = __half22float2(h01);
    float2 v23 = __half22float2(h23);
#pragma unroll
    for (int k = 0; k < YPT; ++k) {
      int t = j - k;
      if (t >= 0 && t <= 16) {
        float gk = GK[t];
        acc[k][0] += gk * v01.x;
        acc[k][1] += gk * v01.y;
        acc[k][2] += gk * v23.x;
        acc[k][3] += gk * v23.y;
      }
    }
  }
#pragma unroll
  for (int k = 0; k < YPT; ++k) {
    uint2 o;
    __half2 h01 = __float22half2_rn(make_float2(acc[k][0], acc[k][1]));
    __half2 h23 = __float22half2_rn(make_float2(acc[k][2], acc[k][3]));
    o.x = *(unsigned*)&h01;
    o.y = *(unsigned*)&h23;
    *(uint2*)&Bp[(size_t)(y0 + k) * Ww + x0] = o;
  }
}

// ---------------------------------------------------------------------------
// Pass 3: horizontal 17-tap blur + clip + compose (R3 structure: 512-px row
// tiles, 2 px/thread, 6 contiguous out floats per thread). Fully-clean tiles
// take a pure float4 img->out copy (no B stage, no taps).
// ---------------------------------------------------------------------------
__global__ __launch_bounds__(256) void hblur_compose(
    const __half* __restrict__ B, const float* __restrict__ img,
    float* __restrict__ out) {
  __shared__ float tile[528 + 1];
  int tid = threadIdx.x;
  int xs = blockIdx.x * 512;
  int y = blockIdx.y;

  // Fully-clean fast path: straight copy, 384 float4 per (row-tile x 3ch).
  int mdx = max(abs(1024 - xs), abs(1024 - (xs + 511)));
  int mdy = abs(1024 - y);
  if (xs >= 2 && xs + 511 <= 2046 && y >= 2 && y <= 2046 &&
      mdx * mdx + mdy * mdy < CLEAN_D2) {
    const float4* s4 = (const float4*)(img + (size_t)(y * Ww + xs) * 3);
    float4* d4 = (float4*)(out + (size_t)(y * Ww + xs) * 3);
    for (int e = tid; e < 384; e += 256) d4[e] = s4[e];
    return;
  }

  float br[3][2];
  for (int c = 0; c < 3; ++c) {
    const __half* Bp = B + (size_t)c * HW + (size_t)y * Ww;
    __syncthreads();  // protect tile from previous channel's readers
    for (int e = tid; e < 264; e += 256) {
      int xg = xs - 8 + 2 * e;
      float2 v;
      if (xg >= 0 && xg + 1 <= Ww - 1) {
        __half2 h = *(const __half2*)&Bp[xg];
        v = __half22float2(h);
      } else {
        int xlo = xg < 0 ? 0 : (xg > Ww - 1 ? Ww - 1 : xg);
        int xhi = xg + 1 < 0 ? 0 : (xg + 1 > Ww - 1 ? Ww - 1 : xg + 1);
        v = make_float2(__half2float(Bp[xlo]), __half2float(Bp[xhi]));
      }
      *(float2*)&tile[2 * e] = v;
    }
    __syncthreads();
    float f[19];
#pragma unroll
    for (int j = 0; j < 19; ++j) f[j] = tile[2 * tid + j];
    float s0 = 0.f, s1 = 0.f;
#pragma unroll
    for (int j = 0; j < 17; ++j) {
      s0 += GK[j] * f[j];
      s1 += GK[j] * f[j + 1];
    }
    br[c][0] = s0;
    br[c][1] = s1;
  }

  int x = xs + 2 * tid;
#pragma unroll
  for (int u = 0; u < 2; ++u) {
    int xu = x + u;
    int dx = 1024 - xu, dy = 1024 - y;
    bool clean = (xu >= 2 && xu <= 2046 && y >= 2 && y <= 2046 &&
                  dx * dx + dy * dy < CLEAN_D2);
    int p3 = (y * Ww + xu) * 3;
    if (clean) {
      out[p3 + 0] = img[p3 + 0];
      out[p3 + 1] = img[p3 + 1];
      out[p3 + 2] = img[p3 + 2];
    } else {
#pragma unroll
      for (int c = 0; c < 3; ++c) {
        float v = br[c][u];
        v = v < 0.f ? 0.f : (v > 255.f ? 255.f : v);
        out[p3 + c] = v;
      }
    }
  }
}

extern "C" void kernel_launch(void* const* d_in, const int* in_sizes, int n_in,
                              void* d_out, int out_size, void* d_ws,
                              size_t ws_size, hipStream_t stream) {
  const float* img = (const float*)d_in[0];
  const int* off = (const int*)d_in[1];
  float* out = (float*)d_out;

  // Workspace: A (fp16 x 3 planes, 24 MB) | B (fp16 x 3 planes, 24 MB)
  __half* A = (__half*)d_ws;
  __half* Bp = A + (size_t)3 * HW;

  swap_gather<<<dim3(Ww / TX, Hh / TY), 256, 0, stream>>>(img, off, A);
  vblur<<<768, 256, 0, stream>>>(A, Bp);
  hblur_compose<<<dim3(Ww / 512, Hh), 256, 0, stream>>>(Bp, img, out);
}